// Round 7
// baseline (71.502 us; speedup 1.0000x reference)
//
#include <hip/hip_runtime.h>
#include <hip/hip_bf16.h>
#include <math.h>

#define KCURV  0.1f
#define KK     0.010000001f          // k*k
#define SQRT_K 0.31622776601683794f
#define TWO_SQRT_K 0.6324555320336759f
#define INV_SQRT_K 3.1622776601683795f
#define TD 64   // feature dim D

typedef __bf16  bf16x8  __attribute__((ext_vector_type(8)));
typedef float   f32x4   __attribute__((ext_vector_type(4)));

__device__ __forceinline__ unsigned short f2bf(float f) {
    __hip_bfloat16 h = __float2bfloat16(f);
    return *(unsigned short*)&h;
}

// Single fused kernel: no LDS, no barriers, no workspace, one dispatch.
// wave w -> rows rb+16w..+15; classes cb..cb+63 via 4 MFMA tiles.
// Key identity: lanes sharing m16 (the 4 quads) jointly hold ALL 64 k of
// their row (k = quad*8+j and 32+quad*8+j), so shfl_xor(16)+shfl_xor(32)
// yields exact fp32 full-row reductions — used for y2 (X rows) AND for the
// per-class hyperbolic transform (P/A rows), replacing the prep kernel.
// Fragment layouts (validated rounds 4-6):
//   A[m=lane&15][k=quad*8+j] ; B[k=quad*8+j][n=lane&15] ;
//   C/D: col=lane&15, row=quad*4+reg
__global__ __launch_bounds__(256) void mlr_fused_kernel(
    const float* __restrict__ x, const float* __restrict__ a_vals,
    const float* __restrict__ p_vals, float* __restrict__ out, int B, int C)
{
    const int tid  = threadIdx.x;
    const int w    = tid >> 6;
    const int lane = tid & 63;
    const int m16  = lane & 15;
    const int quad = lane >> 4;
    const int cb   = blockIdx.x * 64;
    const int rb   = blockIdx.y * 64;
    int arow = rb + 16 * w + m16; if (arow >= B) arow = B - 1;

    // ---- X row slices (fp32, independent loads issued first) ----
    float xv[16];                      // [0:8)=k quad*8+j ; [8:16)=+32
    {
        const float* xr = x + (size_t)arow * TD + quad * 8;
        *(float4*)&xv[0]  = *(const float4*)xr;
        *(float4*)&xv[4]  = *(const float4*)(xr + 4);
        *(float4*)&xv[8]  = *(const float4*)(xr + 32);
        *(float4*)&xv[12] = *(const float4*)(xr + 36);
    }

    // ---- class row slices (fp32) for the 4 B-tiles ----
    float pv[4][16], av[4][16];
    #pragma unroll
    for (int t = 0; t < 4; ++t) {
        int cl = cb + 16 * t + m16; if (cl >= C) cl = C - 1;  // clamped pad
        const float* pr = p_vals + (size_t)cl * TD + quad * 8;
        const float* ar = a_vals + (size_t)cl * TD + quad * 8;
        *(float4*)&pv[t][0]  = *(const float4*)pr;
        *(float4*)&pv[t][4]  = *(const float4*)(pr + 4);
        *(float4*)&pv[t][8]  = *(const float4*)(pr + 32);
        *(float4*)&pv[t][12] = *(const float4*)(pr + 36);
        *(float4*)&av[t][0]  = *(const float4*)ar;
        *(float4*)&av[t][4]  = *(const float4*)(ar + 4);
        *(float4*)&av[t][8]  = *(const float4*)(ar + 32);
        *(float4*)&av[t][12] = *(const float4*)(ar + 36);
    }

    // ---- y2: exact fp32 row norms + rebroadcast to C-layout rows ----
    float s = 0.f;
    #pragma unroll
    for (int u = 0; u < 16; ++u) s = fmaf(xv[u], xv[u], s);
    s += __shfl_xor(s, 16, 64);
    s += __shfl_xor(s, 32, 64);
    float y2r[4];
    #pragma unroll
    for (int r = 0; r < 4; ++r) y2r[r] = __shfl(s, quad * 4 + r, 64);

    // ---- A-fragments (bf16) ----
    bf16x8 af[2];
    #pragma unroll
    for (int step = 0; step < 2; ++step) {
        union { unsigned short u[8]; bf16x8 v; } cv;
        #pragma unroll
        for (int u = 0; u < 8; ++u) cv.u[u] = f2bf(xv[step * 8 + u]);
        af[step] = cv.v;
    }

    // ---- per-tile: in-register class transform -> B-frags -> MFMA ----
    f32x4 accP[4], accA[4];
    float x2c[4], pac[4], anc[4], scc[4];
    #pragma unroll
    for (int t = 0; t < 4; ++t) {
        float s_pp = 0.f, s_aa = 0.f, s_pa = 0.f;
        #pragma unroll
        for (int u = 0; u < 16; ++u) {
            s_pp = fmaf(pv[t][u], pv[t][u], s_pp);
            s_aa = fmaf(av[t][u], av[t][u], s_aa);
            s_pa = fmaf(pv[t][u], av[t][u], s_pa);
        }
        s_pp += __shfl_xor(s_pp, 16, 64); s_pp += __shfl_xor(s_pp, 32, 64);
        s_aa += __shfl_xor(s_aa, 16, 64); s_aa += __shfl_xor(s_aa, 32, 64);
        s_pa += __shfl_xor(s_pa, 16, 64); s_pa += __shfl_xor(s_pa, 32, 64);

        float pn = sqrtf(s_pp); if (pn < 1e-15f) pn = 1e-15f;
        float arg = SQRT_K * pn;
        float th = tanhf(arg);
        float factor = th / arg;                // p_poin = factor * p
        float p2 = factor * factor * s_pp;      // ||p_poin||^2
        float ca = 1.0f + KCURV * p2;           // a_poin = ca * a
        float anorm = ca * sqrtf(s_aa); if (anorm < 1e-15f) anorm = 1e-15f;
        float lam = 2.0f / (1.0f - KCURV * p2);
        x2c[t] = p2;
        pac[t] = -factor * ca * s_pa;           // sum(mp * a_poin)
        anc[t] = anorm;
        scc[t] = lam * anorm * INV_SQRT_K;

        bf16x8 bp[2], ba[2];
        #pragma unroll
        for (int step = 0; step < 2; ++step) {
            union { unsigned short u[8]; bf16x8 v; } cp, cab;
            #pragma unroll
            for (int u = 0; u < 8; ++u) {
                cp.u[u]  = f2bf(-factor * pv[t][step * 8 + u]);
                cab.u[u] = f2bf(ca * av[t][step * 8 + u]);
            }
            bp[step] = cp.v; ba[step] = cab.v;
        }

        f32x4 zp = (f32x4){0.f, 0.f, 0.f, 0.f};
        f32x4 za = (f32x4){0.f, 0.f, 0.f, 0.f};
        zp = __builtin_amdgcn_mfma_f32_16x16x32_bf16(af[0], bp[0], zp, 0, 0, 0);
        zp = __builtin_amdgcn_mfma_f32_16x16x32_bf16(af[1], bp[1], zp, 0, 0, 0);
        za = __builtin_amdgcn_mfma_f32_16x16x32_bf16(af[0], ba[0], za, 0, 0, 0);
        za = __builtin_amdgcn_mfma_f32_16x16x32_bf16(af[1], ba[1], za, 0, 0, 0);
        accP[t] = zp; accA[t] = za;
    }

    // ---- epilogue + store (all class scalars already in-register) ----
    #pragma unroll
    for (int t = 0; t < 4; ++t) {
        const int cl = cb + 16 * t + m16;
        const float x2 = x2c[t], pa = pac[t], an = anc[t], sc = scc[t];
        const float beta = 1.0f - KCURV * x2;
        const float kkx2 = KK * x2;
        #pragma unroll
        for (int r = 0; r < 4; ++r) {
            const int gr = rb + 16 * w + quad * 4 + r;
            const float y2 = y2r[r];
            const float xy = accP[t][r];
            const float xa = accA[t][r];
            float t1    = fmaf(2.0f * KCURV, xy, 1.0f);
            float den   = fmaf(kkx2, y2, t1);                 // mobius denom
            float alpha = fmaf(KCURV, y2, t1);
            float g     = fmaf(alpha, pa, beta * xa);
            float M     = fmaf(alpha * alpha, x2,
                          fmaf(2.0f * alpha * beta, xy, beta * beta * y2));
            // z = 2√k·g·den / (an·(den² - k·M))  (single reciprocal)
            float dd    = fmaf(den, den, -KCURV * M);
            float z     = TWO_SQRT_K * g * den * __builtin_amdgcn_rcpf(an * dd);
            float lg    = sc * __logf(z + sqrtf(fmaf(z, z, 1.0f)));   // asinh
            if (cl < C && gr < B) out[(size_t)gr * C + cl] = lg;
        }
    }
}

extern "C" void kernel_launch(void* const* d_in, const int* in_sizes, int n_in,
                              void* d_out, int out_size, void* d_ws, size_t ws_size,
                              hipStream_t stream) {
    const float* x      = (const float*)d_in[0];
    const float* a_vals = (const float*)d_in[1];
    const float* p_vals = (const float*)d_in[2];
    const int B = in_sizes[0] / TD;
    const int C = in_sizes[1] / TD;
    const int rowBlocks = (B + 63) / 64;
    const int clsBlocks = (C + 63) / 64;

    dim3 grid(clsBlocks, rowBlocks);
    mlr_fused_kernel<<<grid, dim3(256), 0, stream>>>(
        x, a_vals, p_vals, (float*)d_out, B, C);
}

// Round 8
// 69.963 us; speedup vs baseline: 1.0220x; 1.0220x over previous
//
#include <hip/hip_runtime.h>
#include <hip/hip_bf16.h>
#include <math.h>

#define KCURV  0.1f
#define KK     0.010000001f          // k*k
#define SQRT_K 0.31622776601683794f
#define TWO_SQRT_K 0.6324555320336759f
#define INV_SQRT_K 3.1622776601683795f
#define TD 64   // feature dim D

typedef __bf16  bf16x8  __attribute__((ext_vector_type(8)));
typedef float   f32x4   __attribute__((ext_vector_type(4)));

__device__ __forceinline__ unsigned short f2bf(float f) {
    __hip_bfloat16 h = __float2bfloat16(f);
    return *(unsigned short*)&h;
}

// ---------------- kernel 1: class-operand prep (16 blocks, latency-bound) --
// classes -> Pbf/Abf (bf16, row-major k-contiguous) + per-class scalars
__global__ __launch_bounds__(256) void prep_kernel(
    const float* __restrict__ a_vals, const float* __restrict__ p_vals,
    unsigned short* __restrict__ Pbf, unsigned short* __restrict__ Abf,
    float* __restrict__ x2g, float* __restrict__ pag,
    float* __restrict__ ang, float* __restrict__ scg,
    int C)
{
    const int tid  = threadIdx.x;
    const int item = blockIdx.x * 64 + (tid >> 2);
    const int q    = tid & 3;
    const int gc   = item < C ? item : C - 1;   // pad tail with clamped copy

    const float* pr = p_vals + (size_t)gc * TD + q * 16;
    const float* ar = a_vals + (size_t)gc * TD + q * 16;
    float pv[16], av[16];
    #pragma unroll
    for (int m = 0; m < 4; ++m) {
        *(float4*)&pv[m * 4] = *(const float4*)(pr + m * 4);
        *(float4*)&av[m * 4] = *(const float4*)(ar + m * 4);
    }
    float s_pp = 0.f, s_aa = 0.f, s_pa = 0.f;
    #pragma unroll
    for (int u = 0; u < 16; ++u) {
        s_pp = fmaf(pv[u], pv[u], s_pp);
        s_aa = fmaf(av[u], av[u], s_aa);
        s_pa = fmaf(pv[u], av[u], s_pa);
    }
    s_pp += __shfl_xor(s_pp, 1, 64); s_pp += __shfl_xor(s_pp, 2, 64);
    s_aa += __shfl_xor(s_aa, 1, 64); s_aa += __shfl_xor(s_aa, 2, 64);
    s_pa += __shfl_xor(s_pa, 1, 64); s_pa += __shfl_xor(s_pa, 2, 64);

    float pn = sqrtf(s_pp); if (pn < 1e-15f) pn = 1e-15f;
    float arg = SQRT_K * pn;
    float t = tanhf(arg);
    float factor = t / arg;                 // p_poin = factor * p
    float p2 = factor * factor * s_pp;      // ||p_poin||^2
    float ca = 1.0f + KCURV * p2;           // a_poin = ca * a
    float anorm = ca * sqrtf(s_aa); if (anorm < 1e-15f) anorm = 1e-15f;
    float lam = 2.0f / (1.0f - KCURV * p2);
    float scale = lam * anorm * INV_SQRT_K;
    float pa = -factor * ca * s_pa;         // sum(mp * a_poin)

    if (q == 0) {
        x2g[item] = p2; pag[item] = pa; ang[item] = anorm; scg[item] = scale;
    }
    unsigned short ubp[16], uba[16];
    #pragma unroll
    for (int u = 0; u < 16; ++u) {
        ubp[u] = f2bf(-factor * pv[u]);
        uba[u] = f2bf(ca * av[u]);
    }
    unsigned short* dp = Pbf + (size_t)item * TD + q * 16;
    unsigned short* da = Abf + (size_t)item * TD + q * 16;
    *(ulonglong2*)dp       = *(const ulonglong2*)&ubp[0];
    *(ulonglong2*)(dp + 8) = *(const ulonglong2*)&ubp[8];
    *(ulonglong2*)da       = *(const ulonglong2*)&uba[0];
    *(ulonglong2*)(da + 8) = *(const ulonglong2*)&uba[8];
}

// ---------------- kernel 2: LDS-free MFMA dual-GEMM + epilogue -------------
// wave w -> rows rb+16w..+15, all 64 classes of the tile. No LDS, no
// barriers. X is read as raw fp32 (independent of prep), converted to bf16
// in-register; y2 computed in-wave: lanes sharing m16 jointly hold all 64 k
// of their A-row, so Σv² + shfl_xor(16,32) = exact fp32 row norm.
__global__ __launch_bounds__(256) void mlr_gemm_kernel(
    const float* __restrict__ x,
    const unsigned short* __restrict__ Pbf, const unsigned short* __restrict__ Abf,
    const float* __restrict__ x2g, const float* __restrict__ pag,
    const float* __restrict__ ang, const float* __restrict__ scg,
    float* __restrict__ out, int B, int C)
{
    const int tid  = threadIdx.x;
    const int w    = tid >> 6;
    const int lane = tid & 63;
    const int m16  = lane & 15;
    const int quad = lane >> 4;
    const int cb   = blockIdx.x * 64;
    const int rb   = blockIdx.y * 64;
    int arow = rb + 16 * w + m16; if (arow >= B) arow = B - 1;

    // A-frag: A[m=lane&15][k=quad*8+j]; B-frag same addressing on class rows;
    // C/D: col=lane&15, row=quad*4+reg  (validated end-to-end in rounds 4-7)
    float xv[2][8];
    bf16x8 bp[4][2], ba[4][2];
    #pragma unroll
    for (int step = 0; step < 2; ++step) {
        const int ko = quad * 8 + step * 32;
        const float* xr = x + (size_t)arow * TD + ko;
        *(float4*)&xv[step][0] = *(const float4*)xr;
        *(float4*)&xv[step][4] = *(const float4*)(xr + 4);
        #pragma unroll
        for (int t = 0; t < 4; ++t) {
            const size_t crow = (size_t)(cb + 16 * t + m16) * TD + ko;
            bp[t][step] = *(const bf16x8*)(Pbf + crow);
            ba[t][step] = *(const bf16x8*)(Abf + crow);
        }
    }

    // y2: exact fp32 row norms, then rebroadcast to C-layout rows
    float s = 0.f;
    #pragma unroll
    for (int step = 0; step < 2; ++step)
        #pragma unroll
        for (int u = 0; u < 8; ++u) s = fmaf(xv[step][u], xv[step][u], s);
    s += __shfl_xor(s, 16, 64);
    s += __shfl_xor(s, 32, 64);
    float y2r[4];
    #pragma unroll
    for (int r = 0; r < 4; ++r) y2r[r] = __shfl(s, quad * 4 + r, 64);

    // fp32 -> bf16 A-fragments
    bf16x8 af[2];
    #pragma unroll
    for (int step = 0; step < 2; ++step) {
        union { unsigned short u[8]; bf16x8 v; } cv;
        #pragma unroll
        for (int u = 0; u < 8; ++u) cv.u[u] = f2bf(xv[step][u]);
        af[step] = cv.v;
    }

    f32x4 accP[4], accA[4];
    #pragma unroll
    for (int t = 0; t < 4; ++t) {
        accP[t] = (f32x4){0.f, 0.f, 0.f, 0.f};
        accA[t] = (f32x4){0.f, 0.f, 0.f, 0.f};
    }
    #pragma unroll
    for (int step = 0; step < 2; ++step) {
        #pragma unroll
        for (int t = 0; t < 4; ++t) {
            accP[t] = __builtin_amdgcn_mfma_f32_16x16x32_bf16(af[step], bp[t][step], accP[t], 0, 0, 0);
            accA[t] = __builtin_amdgcn_mfma_f32_16x16x32_bf16(af[step], ba[t][step], accA[t], 0, 0, 0);
        }
    }

    #pragma unroll
    for (int t = 0; t < 4; ++t) {
        const int cl = cb + 16 * t + m16;
        const float x2 = x2g[cl], pa = pag[cl], an = ang[cl], sc = scg[cl];
        const float beta = 1.0f - KCURV * x2;
        const float kkx2 = KK * x2;
        #pragma unroll
        for (int r = 0; r < 4; ++r) {
            const int gr = rb + 16 * w + quad * 4 + r;
            const float y2 = y2r[r];
            const float xy = accP[t][r];
            const float xa = accA[t][r];
            float t1    = fmaf(2.0f * KCURV, xy, 1.0f);
            float den   = fmaf(kkx2, y2, t1);                 // mobius denom
            float alpha = fmaf(KCURV, y2, t1);
            float g     = fmaf(alpha, pa, beta * xa);
            float M     = fmaf(alpha * alpha, x2,
                          fmaf(2.0f * alpha * beta, xy, beta * beta * y2));
            // z = 2√k·g·den / (an·(den² - k·M))  (single reciprocal)
            float dd    = fmaf(den, den, -KCURV * M);
            float z     = TWO_SQRT_K * g * den * __builtin_amdgcn_rcpf(an * dd);
            float lg    = sc * __logf(z + sqrtf(fmaf(z, z, 1.0f)));   // asinh
            if (cl < C && gr < B) out[(size_t)gr * C + cl] = lg;
        }
    }
}

extern "C" void kernel_launch(void* const* d_in, const int* in_sizes, int n_in,
                              void* d_out, int out_size, void* d_ws, size_t ws_size,
                              hipStream_t stream) {
    const float* x      = (const float*)d_in[0];
    const float* a_vals = (const float*)d_in[1];
    const float* p_vals = (const float*)d_in[2];
    const int B = in_sizes[0] / TD;
    const int C = in_sizes[1] / TD;
    const int rowBlocks = (B + 63) / 64;
    const int clsBlocks = (C + 63) / 64;
    const int CPAD = clsBlocks * 64;

    char* ws = (char*)d_ws;
    unsigned short* Pbf = (unsigned short*)ws;
    unsigned short* Abf = (unsigned short*)(ws + (size_t)CPAD * TD * 2);
    float* x2g = (float*)(ws + (size_t)CPAD * TD * 4);
    float* pag = x2g + CPAD;
    float* ang = pag + CPAD;
    float* scg = ang + CPAD;

    prep_kernel<<<clsBlocks, 256, 0, stream>>>(
        a_vals, p_vals, Pbf, Abf, x2g, pag, ang, scg, C);

    dim3 grid(clsBlocks, rowBlocks);
    mlr_gemm_kernel<<<grid, dim3(256), 0, stream>>>(
        x, Pbf, Abf, x2g, pag, ang, scg, (float*)d_out, B, C);
}